// Round 10
// baseline (1090.068 us; speedup 1.0000x reference)
//
#include <hip/hip_runtime.h>
#include <math.h>

#define G_   8
#define NPG_ 4096
#define HC_  16
#define LAT_ 64
#define FF_  512
#define EDIM_ 3
#define EH_  64
#define NN_  32768
#define EE_  393216

typedef float v2f __attribute__((ext_vector_type(2)));
typedef float v4f __attribute__((ext_vector_type(4)));

#if __has_builtin(__builtin_elementwise_fma) && __has_builtin(__builtin_elementwise_max)
static __device__ __forceinline__ v2f pkfma2(v2f a, v2f b, v2f c) {
  return __builtin_elementwise_fma(a, b, c);
}
static __device__ __forceinline__ v4f pkfma4(v4f a, v4f b, v4f c) {
  return __builtin_elementwise_fma(a, b, c);
}
static __device__ __forceinline__ v2f pkmax2(v2f a, v2f b) {
  return __builtin_elementwise_max(a, b);
}
#else
static __device__ __forceinline__ v2f pkfma2(v2f a, v2f b, v2f c) {
  v2f r; r.x = fmaf(a.x, b.x, c.x); r.y = fmaf(a.y, b.y, c.y); return r;
}
static __device__ __forceinline__ v4f pkfma4(v4f a, v4f b, v4f c) {
  v4f r; r.x = fmaf(a.x, b.x, c.x); r.y = fmaf(a.y, b.y, c.y);
  r.z = fmaf(a.z, b.z, c.z); r.w = fmaf(a.w, b.w, c.w); return r;
}
static __device__ __forceinline__ v2f pkmax2(v2f a, v2f b) {
  v2f r; r.x = fmaxf(a.x, b.x); r.y = fmaxf(a.y, b.y); return r;
}
#endif

// ---------------- front-end ----------------
__global__ void k_front1(const float* __restrict__ x, const float* __restrict__ w,
                         const float* __restrict__ b, float* __restrict__ h1) {
  int c = blockIdx.x * blockDim.x + threadIdx.x;
  if (c >= FF_) return;
  float acc[G_];
#pragma unroll
  for (int g = 0; g < G_; g++) acc[g] = 0.f;
  for (int r = 0; r < LAT_; r++) {
    float wv = w[r * FF_ + c];
#pragma unroll
    for (int g = 0; g < G_; g++) acc[g] = fmaf(x[g * LAT_ + r], wv, acc[g]);
  }
#pragma unroll
  for (int g = 0; g < G_; g++) h1[g * FF_ + c] = acc[g] + b[c];
}

__global__ __launch_bounds__(512) void k_front2(const float* __restrict__ h1,
                                                const float* __restrict__ w,
                                                const float* __restrict__ b,
                                                float* __restrict__ hn) {
  __shared__ float sh[G_ * FF_];
  for (int i = threadIdx.x; i < G_ * FF_; i += blockDim.x) sh[i] = h1[i];
  __syncthreads();
  int g = threadIdx.x >> 6;
  int lane = threadIdx.x & 63;
  int c = blockIdx.x * 64 + lane;
  const float* shg = &sh[g * FF_];
  float acc = 0.f;
#pragma unroll 8
  for (int r = 0; r < FF_; r++) acc = fmaf(shg[r], w[r * (NPG_ * HC_) + c], acc);
  float v = acc + b[c];
  hn[g * (NPG_ * HC_) + c] = v > 0.f ? v : expm1f(v);
}

// ---------------- counting sort by src ----------------
__global__ void k_zero(int* __restrict__ p, int nv) {
  int i = blockIdx.x * blockDim.x + threadIdx.x;
  if (i < nv) p[i] = 0;
}
__global__ void k_hist(const int* __restrict__ key, int* __restrict__ cnt) {
  int e = blockIdx.x * blockDim.x + threadIdx.x;
  if (e < EE_) atomicAdd(&cnt[key[e]], 1);
}
__global__ __launch_bounds__(1024) void k_scan(const int* __restrict__ cnt,
                                               int* __restrict__ rowptr,
                                               int* __restrict__ cursor) {
  __shared__ int part[1024];
  int t = threadIdx.x;
  int base = t * 32;
  int loc[32];
  int s = 0;
#pragma unroll
  for (int i = 0; i < 32; i++) { loc[i] = s; s += cnt[base + i]; }
  part[t] = s;
  __syncthreads();
  for (int off = 1; off < 1024; off <<= 1) {
    int v = (t >= off) ? part[t - off] : 0;
    __syncthreads();
    part[t] += v;
    __syncthreads();
  }
  int pre = (t == 0) ? 0 : part[t - 1];
#pragma unroll
  for (int i = 0; i < 32; i++) {
    int v = pre + loc[i];
    rowptr[base + i] = v;
    cursor[base + i] = v;
  }
  if (t == 1023) rowptr[NN_] = part[1023];
}
// fused scatter+gather: place edge data directly at its src-sorted slot
__global__ void k_scatter(const int* __restrict__ src, const int* __restrict__ dst,
                          const float* __restrict__ ea, int* __restrict__ cursor,
                          float4* __restrict__ eas4) {
  int e = blockIdx.x * blockDim.x + threadIdx.x;
  if (e < EE_) {
    int pos = atomicAdd(&cursor[src[e]], 1);
    eas4[pos] = make_float4(ea[e * 3], ea[e * 3 + 1], ea[e * 3 + 2],
                            __int_as_float(dst[e]));
  } else if (e < EE_ + 8) {
    eas4[e] = make_float4(0.f, 0.f, 0.f, __int_as_float(0));
  }
}

// ---------------- per-conv kernels ----------------
__global__ void k_nodeinit(const float* __restrict__ hn, const float* __restrict__ root,
                           const float* __restrict__ bias, float* __restrict__ out) {
  int idx = blockIdx.x * blockDim.x + threadIdx.x;
  if (idx >= NN_ * HC_) return;
  int nd = idx >> 4, o = idx & 15;
  float acc = bias[o];
#pragma unroll
  for (int i = 0; i < 16; i++) acc = fmaf(hn[nd * 16 + i], root[i * 16 + o], acc);
  out[idx] = acc;
}

// W2m lane-fast: W2m[i*1024 + j4*256 + l*4 + c] = w2[h*256 + i*16 + o],
//   h = (l>>4)*16 + j4*4 + c, o = l&15.
// w1d8: per h, duplicated weight pairs {x,x,y,y,z,z,b,b} (for v_pk_fma).
__global__ void k_wprep(const float* __restrict__ w2, const float* __restrict__ w1,
                        const float* __restrict__ b1, float* __restrict__ W2m,
                        float* __restrict__ w1d8) {
  int idx = blockIdx.x * 256 + threadIdx.x;
  if (idx < 16384) {
    int i  = idx >> 10;
    int j4 = (idx >> 8) & 3;
    int l  = (idx >> 2) & 63;
    int c  = idx & 3;
    int q = l >> 4, o = l & 15;
    int h = q * 16 + j4 * 4 + c;
    W2m[idx] = w2[h * 256 + i * 16 + o];
  }
  if (idx < 64) {
    int h = idx;
    w1d8[h * 8 + 0] = w1[h];        w1d8[h * 8 + 1] = w1[h];
    w1d8[h * 8 + 2] = w1[64 + h];   w1d8[h * 8 + 3] = w1[64 + h];
    w1d8[h * 8 + 4] = w1[128 + h];  w1d8[h * 8 + 5] = w1[128 + h];
    w1d8[h * 8 + 6] = b1[h];        w1d8[h * 8 + 7] = b1[h];
  }
}

// Edge aggregation. One wave per source node, no LDS, M computed inline from
// L1/L2-resident W2m (lane-contiguous loads). j-loop uses packed fp32
// (v_pk_fma_f32) over edge pairs; weights pre-duplicated in w1d8.
__global__ __launch_bounds__(256, 4) void k_edge(
    const float* __restrict__ hn, const int* __restrict__ rowptr,
    const float4* __restrict__ eas4, const float* __restrict__ w1d8,
    const float* __restrict__ b2, const float* __restrict__ W2m,
    float* __restrict__ hnext) {
  int tid = threadIdx.x;
  int wave = tid >> 6, l = tid & 63;
  int o = l & 15, q = l >> 4;
  int n = blockIdx.x * 4 + wave;

  int rs = rowptr[n], re = rowptr[n + 1];
  if (rs >= re) return;

  // inline M-setup: A[j4][c] = M_n[h=q*16+j4*4+c][o]
  const v4f* __restrict__ W2m4v = (const v4f*)W2m;
  const v4f* __restrict__ hx4 = (const v4f*)&hn[n * 16];
  v4f A0 = 0.f, A1 = 0.f, A2 = 0.f, A3 = 0.f;
  float T = 0.f;
#pragma unroll
  for (int i4 = 0; i4 < 4; i4++) {
    v4f xq = hx4[i4];
#pragma unroll
    for (int s = 0; s < 4; s++) {
      int i = i4 * 4 + s;
      float xi = xq[s];
      T = fmaf(xi, b2[i * 16 + o], T);
      v4f xs = {xi, xi, xi, xi};
      A0 = pkfma4(xs, W2m4v[i * 256 + l], A0);
      A1 = pkfma4(xs, W2m4v[i * 256 + 64 + l], A1);
      A2 = pkfma4(xs, W2m4v[i * 256 + 128 + l], A2);
      A3 = pkfma4(xs, W2m4v[i * 256 + 192 + l], A3);
    }
  }
  // M2[j] = {M[j], M[j]} for packed accumulation
  v2f M2[16];
#pragma unroll
  for (int c = 0; c < 4; c++) {
    M2[c]      = (v2f){A0[c], A0[c]};
    M2[4 + c]  = (v2f){A1[c], A1[c]};
    M2[8 + c]  = (v2f){A2[c], A2[c]};
    M2[12 + c] = (v2f){A3[c], A3[c]};
  }

  const v4f* __restrict__ w1v = (const v4f*)&w1d8[q * 16 * 8];

  float4 c0 = eas4[rs], c1 = eas4[rs + 1], c2 = eas4[rs + 2], c3 = eas4[rs + 3];
  for (int k = rs; k < re; k += 4) {
    float4 n0 = eas4[k + 4], n1 = eas4[k + 5], n2 = eas4[k + 6], n3 = eas4[k + 7];

    v2f eXa = {c0.x, c1.x}, eYa = {c0.y, c1.y}, eZa = {c0.z, c1.z};
    v2f eXb = {c2.x, c3.x}, eYb = {c2.y, c3.y}, eZb = {c2.z, c3.z};
    v2f pA = {0.f, 0.f}, pB = {0.f, 0.f};
    v2f z2 = {0.f, 0.f};
#pragma unroll
    for (int j = 0; j < 16; j++) {
      v4f wa = w1v[j * 2];      // {x,x,y,y}
      v4f wb = w1v[j * 2 + 1];  // {z,z,b,b}
      v2f wx = __builtin_shufflevector(wa, wa, 0, 1);
      v2f wy = __builtin_shufflevector(wa, wa, 2, 3);
      v2f wz = __builtin_shufflevector(wb, wb, 0, 1);
      v2f wc = __builtin_shufflevector(wb, wb, 2, 3);
      v2f hA = pkmax2(pkfma2(eZa, wz, pkfma2(eYa, wy, pkfma2(eXa, wx, wc))), z2);
      v2f hB = pkmax2(pkfma2(eZb, wz, pkfma2(eYb, wy, pkfma2(eXb, wx, wc))), z2);
      pA = pkfma2(hA, M2[j], pA);
      pB = pkfma2(hB, M2[j], pB);
    }
    float p0 = pA.x, p1 = pA.y, p2 = pB.x, p3 = pB.y;
    p0 += __shfl_xor(p0, 16); p1 += __shfl_xor(p1, 16);
    p2 += __shfl_xor(p2, 16); p3 += __shfl_xor(p3, 16);
    p0 += __shfl_xor(p0, 32); p1 += __shfl_xor(p1, 32);
    p2 += __shfl_xor(p2, 32); p3 += __shfl_xor(p3, 32);

    // every lane holds all four reduced sums; lane group q commits edge k+q
    float vv  = (q == 0) ? p0   : (q == 1) ? p1   : (q == 2) ? p2   : p3;
    float dpf = (q == 0) ? c0.w : (q == 1) ? c1.w : (q == 2) ? c2.w : c3.w;
    if (k + q < re) atomicAdd(&hnext[__float_as_int(dpf) * 16 + o], vv + T);

    c0 = n0; c1 = n1; c2 = n2; c3 = n3;
  }
}

__global__ void k_elu(const float* __restrict__ in, float* __restrict__ out) {
  int idx = blockIdx.x * blockDim.x + threadIdx.x;
  if (idx >= NN_ * HC_) return;
  float v = in[idx];
  out[idx] = v > 0.f ? v : expm1f(v);
}

// ---------------- launch ----------------
extern "C" void kernel_launch(void* const* d_in, const int* in_sizes, int n_in,
                              void* d_out, int out_size, void* d_ws, size_t ws_size,
                              hipStream_t stream) {
  const float* x    = (const float*)d_in[0];
  const int*   ei   = (const int*)d_in[1];
  const float* ea   = (const float*)d_in[2];
  const float* fc2w = (const float*)d_in[3];
  const float* fc2b = (const float*)d_in[4];
  const float* fc1w = (const float*)d_in[5];
  const float* fc1b = (const float*)d_in[6];
  float* out = (float*)d_out;

  float* ws = (float*)d_ws;
  float*  h1     = ws;                             // 4096
  float*  hnode  = h1 + 4096;                      // N*16
  float*  hnext  = hnode + (size_t)NN_ * HC_;      // N*16
  float*  W2m    = hnext + (size_t)NN_ * HC_;      // 16384
  float*  w1d8   = W2m + 16384;                    // 512
  float4* eas4   = (float4*)(w1d8 + 512);          // (E+8)*4 floats
  int*    cnt    = (int*)((float*)eas4 + (size_t)(EE_ + 8) * 4);
  int*    rowptr = cnt + NN_;
  int*    cursor = rowptr + NN_ + 1;

  const int* src  = ei;
  const int* dstp = ei + EE_;

  k_front1<<<2, 256, 0, stream>>>(x, fc2w, fc2b, h1);
  k_front2<<<1024, 512, 0, stream>>>(h1, fc1w, fc1b, hnode);

  k_zero<<<(NN_ + 255) / 256, 256, 0, stream>>>(cnt, NN_);
  k_hist<<<(EE_ + 255) / 256, 256, 0, stream>>>(src, cnt);
  k_scan<<<1, 1024, 0, stream>>>(cnt, rowptr, cursor);
  k_scatter<<<(EE_ + 8 + 255) / 256, 256, 0, stream>>>(src, dstp, ea, cursor, eas4);

  for (int cv = 0; cv < 2; cv++) {
    const float* root = (const float*)d_in[7 + cv * 6];
    const float* cb   = (const float*)d_in[8 + cv * 6];
    const float* w1   = (const float*)d_in[9 + cv * 6];
    const float* b1   = (const float*)d_in[10 + cv * 6];
    const float* w2   = (const float*)d_in[11 + cv * 6];
    const float* b2   = (const float*)d_in[12 + cv * 6];
    k_wprep<<<64, 256, 0, stream>>>(w2, w1, b1, W2m, w1d8);
    k_nodeinit<<<NN_ * HC_ / 256, 256, 0, stream>>>(hnode, root, cb, hnext);
    k_edge<<<NN_ / 4, 256, 0, stream>>>(hnode, rowptr, eas4, w1d8, b2, W2m, hnext);
    k_elu<<<NN_ * HC_ / 256, 256, 0, stream>>>(hnext, cv == 0 ? hnode : out);
  }
}